// Round 4
// baseline (804.514 us; speedup 1.0000x reference)
//
#include <hip/hip_runtime.h>
#include <math.h>
#include <utility>

typedef __attribute__((ext_vector_type(8))) short    bf16x8;
typedef __attribute__((ext_vector_type(4))) float    f32x4;
typedef __attribute__((ext_vector_type(2))) unsigned u32x2;

template<int I, int N, class F>
__device__ __forceinline__ void sfor(F&& f) {
    if constexpr (I < N) { f(std::integral_constant<int, I>{}); sfor<I + 1, N>(static_cast<F&&>(f)); }
}

#define NPT    50000
#define NTILES 6250     // 400000 pts / 64 per tile, exact
#define ZIN_S  40       // shorts per zin row (80 B, 16B-aligned)
#define Z_S    136      // shorts per z1/z2 row (272 B; +8 shorts pad -> 4-bank row step)

static __device__ __forceinline__ float sigm(float x) { return __fdividef(1.f, 1.f + __expf(-x)); }
static __device__ __forceinline__ float tanh_fast(float x) {
    float xc = fminf(fmaxf(x, -15.f), 15.f);
    float e  = __expf(2.f * xc);
    return __fdividef(e - 1.f, e + 1.f);
}
static __device__ __forceinline__ unsigned short bf16r(float f) {   // RNE f32->bf16
    unsigned u = __builtin_bit_cast(unsigned, f);
    u += 0x7FFFu + ((u >> 16) & 1u);
    return (unsigned short)(u >> 16);
}

#if defined(__has_builtin)
#if __has_builtin(__builtin_amdgcn_cvt_pk_bf16_f32)
#define HAVE_CVT_PK_BF16 1
#endif
#endif

static __device__ __forceinline__ unsigned packbf(float a, float b) {
#ifdef HAVE_CVT_PK_BF16
    // gfx950 v_cvt_pk_bf16_f32: 2 f32 -> packed bf16, 1 instr (vs ~7 manual)
    return __builtin_bit_cast(unsigned, __builtin_amdgcn_cvt_pk_bf16_f32(a, b));
#else
    return (unsigned)bf16r(a) | ((unsigned)bf16r(b) << 16);
#endif
}
static __device__ __forceinline__ f32x4 mfma16(bf16x8 a, bf16x8 b, f32x4 c) {
    return __builtin_amdgcn_mfma_f32_16x16x32_bf16(a, b, c, 0, 0, 0);
}

// Block = 256 thr = 4 waves, one 64-point tile per block.
// Wave w owns output channels [32w, 32w+32) for layers 1&2 (A-frags resident in
// VGPRs), and points [16w,16w+16) for RK4 state / out-layer.
// Activations pass through LDS in B-frag layout [p][k] (k contiguous bf16).
// launch_bounds(256,4): 4 waves/EU = 16 waves/CU = 4 blocks/CU; VGPR cap 128
// (round-3 used exactly 128), LDS 39936*4 = 159744 <= 160 KiB.
__global__ __launch_bounds__(256, 4) void node_rk4_mfma(
    const float* __restrict__ x0,
    const float* __restrict__ h1_w, const float* __restrict__ h1_b,
    const float* __restrict__ g1_w, const float* __restrict__ g1_b,
    const float* __restrict__ h2_w, const float* __restrict__ h2_b,
    const float* __restrict__ g2_w, const float* __restrict__ g2_b,
    const float* __restrict__ out_w, const float* __restrict__ out_b,
    float* __restrict__ y)
{
    __shared__ __align__(16) short zin[64 * ZIN_S];
    __shared__ __align__(16) short z1s[64 * Z_S];
    __shared__ __align__(16) short z2s[64 * Z_S];

    const int tid  = threadIdx.x;
    const int w    = tid >> 6;        // wave id 0..3
    const int lane = tid & 63;
    const int q    = lane >> 4;       // quad 0..3
    const int m    = lane & 15;       // MFMA row (A) / col (B,C)

    // ---------------- weight preload (once per block) ----------------
    bf16x8 a2h[2][4], a2g[2][4];      // layer2 A-frags: [mtile][kstep]
    bf16x8 a1h[2],    a1g[2];         // layer1 A-frags (K padded 4->32)
    bf16x8 aow[4];                    // out-layer A-frags (M padded 3->16)
    f32x4  b2h[2], b2g[2], b1h[2], b1g[2];   // biases in C-frag layout

    sfor<0, 2>([&](auto MT) {
        constexpr int mt = MT.value;
        const int row = 32 * w + 16 * mt + m;
        sfor<0, 4>([&](auto KS) {
            constexpr int ks = KS.value;
            const float* s1 = h2_w + row * 128 + ks * 32 + q * 8;
            const float* s2 = g2_w + row * 128 + ks * 32 + q * 8;
            bf16x8 t1, t2;
            sfor<0, 8>([&](auto J) {
                constexpr int j = J.value;
                t1[j] = (short)bf16r(s1[j]);
                t2[j] = (short)bf16r(s2[j]);
            });
            a2h[mt][ks] = t1; a2g[mt][ks] = t2;
        });
        bf16x8 t1 = {0,0,0,0,0,0,0,0}, t2 = {0,0,0,0,0,0,0,0};
        if (q == 0) {
            sfor<0, 4>([&](auto J) {
                constexpr int j = J.value;
                t1[j] = (short)bf16r(h1_w[row * 4 + j]);
                t2[j] = (short)bf16r(g1_w[row * 4 + j]);
            });
        }
        a1h[mt] = t1; a1g[mt] = t2;
        const int ob = 32 * w + 16 * mt + 4 * q;
        f32x4 bh, bg, ch, cg;
        sfor<0, 4>([&](auto R) {
            constexpr int r = R.value;
            bh[r] = h2_b[ob + r]; bg[r] = g2_b[ob + r];
            ch[r] = h1_b[ob + r]; cg[r] = g1_b[ob + r];
        });
        b2h[mt] = bh; b2g[mt] = bg; b1h[mt] = ch; b1g[mt] = cg;
    });
    sfor<0, 4>([&](auto KS) {
        constexpr int ks = KS.value;
        bf16x8 t = {0,0,0,0,0,0,0,0};
        if (m < 3) {
            sfor<0, 8>([&](auto J) {
                constexpr int j = J.value;
                t[j] = (short)bf16r(out_w[m * 128 + ks * 32 + q * 8 + j]);
            });
        }
        aow[ks] = t;
    });
    // out-layer bias in C-frag layout: lane holds rows 4q+r; rows 0..2 valid
    f32x4 vob = {0.f, 0.f, 0.f, 0.f};
    if (q == 0) { vob[0] = out_b[0]; vob[1] = out_b[1]; vob[2] = out_b[2]; }

    // zero zin (pad rows k=4..31 must be 0 for the K-padded layer1 MFMA)
    for (int i = tid; i < 64 * ZIN_S / 2; i += 256) ((unsigned*)zin)[i] = 0u;
    __syncthreads();

    const float third = 1.0f / 3.0f;

    for (int tile = blockIdx.x; tile < NTILES; tile += gridDim.x) {
        float xc0 = 0.f, xc1 = 0.f, xc2 = 0.f;
        int gbase = 0;
        if (lane < 16) {
            const int pg = tile * 64 + w * 16 + lane;
            const int bb = pg / NPT;
            const int nn = pg - bb * NPT;
            gbase = bb * 3 * NPT + nn;
            xc0 = x0[gbase]; xc1 = x0[gbase + NPT]; xc2 = x0[gbase + 2 * NPT];
        }
        float k1x=0,k1y=0,k1z=0, k2x=0,k2y=0,k2z=0, k3x=0,k3y=0,k3z=0;
        float ax=0, ay=0, az=0;

        #pragma unroll 1
        for (int s = 0; s < 4; ++s) {
            // ---- stage input -> zin (B-frag rows, lanes 0-15 per wave) ----
            if (lane < 16) {
                float zi0, zi1, zi2, tt;
                if (s == 0)      { zi0 = xc0; zi1 = xc1; zi2 = xc2; tt = 0.f; }
                else if (s == 1) { zi0 = fmaf(k1x, third, xc0);
                                   zi1 = fmaf(k1y, third, xc1);
                                   zi2 = fmaf(k1z, third, xc2); tt = third; }
                else if (s == 2) { zi0 = xc0 + (k2x - k1x * third);
                                   zi1 = xc1 + (k2y - k1y * third);
                                   zi2 = xc2 + (k2z - k1z * third); tt = 2.f * third; }
                else             { zi0 = xc0 + (k1x - k2x + k3x);
                                   zi1 = xc1 + (k1y - k2y + k3y);
                                   zi2 = xc2 + (k1z - k2z + k3z); tt = 1.f; }
                u32x2 pk = { packbf(zi0, zi1), packbf(zi2, tt) };
                *reinterpret_cast<u32x2*>(&zin[(w * 16 + lane) * ZIN_S]) = pk;
            }
            __syncthreads();

            // ---- layer 1 (4->128 via K-padded MFMA); bias preloaded in acc ----
            f32x4 c1h[2][4], c1g[2][4];
            sfor<0, 2>([&](auto MT) { sfor<0, 4>([&](auto NT) {
                c1h[MT.value][NT.value] = b1h[MT.value];
                c1g[MT.value][NT.value] = b1g[MT.value]; }); });
            sfor<0, 4>([&](auto NT) {
                constexpr int nt = NT.value;
                bf16x8 bf = *reinterpret_cast<const bf16x8*>(&zin[(nt * 16 + m) * ZIN_S + q * 8]);
                sfor<0, 2>([&](auto MT) {
                    constexpr int mt = MT.value;
                    c1h[mt][nt] = mfma16(a1h[mt], bf, c1h[mt][nt]);
                    c1g[mt][nt] = mfma16(a1g[mt], bf, c1g[mt][nt]);
                });
            });
            // gate + write z1 B-frags
            sfor<0, 2>([&](auto MT) { sfor<0, 4>([&](auto NT) {
                constexpr int mt = MT.value, nt = NT.value;
                f32x4 h = c1h[mt][nt];
                f32x4 g = c1g[mt][nt];
                float z0  = fmaxf(h[0] * sigm(g[0]), 0.f);
                float z1v = fmaxf(h[1] * sigm(g[1]), 0.f);
                float z2v = fmaxf(h[2] * sigm(g[2]), 0.f);
                float z3  = fmaxf(h[3] * sigm(g[3]), 0.f);
                u32x2 pk = { packbf(z0, z1v), packbf(z2v, z3) };
                *reinterpret_cast<u32x2*>(&z1s[(nt * 16 + m) * Z_S + 32 * w + 16 * mt + 4 * q]) = pk;
            }); });
            __syncthreads();

            // ---- layer 2 (128->128); bias preloaded in acc ----
            f32x4 c2h[2][4], c2g[2][4];
            sfor<0, 2>([&](auto MT) { sfor<0, 4>([&](auto NT) {
                c2h[MT.value][NT.value] = b2h[MT.value];
                c2g[MT.value][NT.value] = b2g[MT.value]; }); });
            sfor<0, 4>([&](auto KS) {
                constexpr int ks = KS.value;
                sfor<0, 4>([&](auto NT) {
                    constexpr int nt = NT.value;
                    bf16x8 bf = *reinterpret_cast<const bf16x8*>(&z1s[(nt * 16 + m) * Z_S + ks * 32 + q * 8]);
                    sfor<0, 2>([&](auto MT) {
                        constexpr int mt = MT.value;
                        c2h[mt][nt] = mfma16(a2h[mt][ks], bf, c2h[mt][nt]);
                        c2g[mt][nt] = mfma16(a2g[mt][ks], bf, c2g[mt][nt]);
                    });
                });
            });
            // gate + write z2 B-frags
            sfor<0, 2>([&](auto MT) { sfor<0, 4>([&](auto NT) {
                constexpr int mt = MT.value, nt = NT.value;
                f32x4 h = c2h[mt][nt];
                f32x4 g = c2g[mt][nt];
                float z0  = fmaxf(h[0] * sigm(g[0]), 0.f);
                float z1v = fmaxf(h[1] * sigm(g[1]), 0.f);
                float z2v = fmaxf(h[2] * sigm(g[2]), 0.f);
                float z3  = fmaxf(h[3] * sigm(g[3]), 0.f);
                u32x2 pk = { packbf(z0, z1v), packbf(z2v, z3) };
                *reinterpret_cast<u32x2*>(&z2s[(nt * 16 + m) * Z_S + 32 * w + 16 * mt + 4 * q]) = pk;
            }); });
            __syncthreads();

            // ---- out layer (128->3, M padded to 16); wave w takes points [16w,16w+16) ----
            f32x4 vc = vob;
            sfor<0, 4>([&](auto KS) {
                constexpr int ks = KS.value;
                bf16x8 bf = *reinterpret_cast<const bf16x8*>(&z2s[(w * 16 + m) * Z_S + ks * 32 + q * 8]);
                vc = mfma16(aow[ks], bf, vc);
            });
            // channels live in quad-0 regs 0..2 (C row = 4q+r)
            const float kx = tanh_fast(vc[0]) * 0.5f;
            const float ky = tanh_fast(vc[1]) * 0.5f;
            const float kz = tanh_fast(vc[2]) * 0.5f;

            if (s == 0)      { k1x=kx;k1y=ky;k1z=kz; ax=kx;ay=ky;az=kz; }
            else if (s == 1) { k2x=kx;k2y=ky;k2z=kz;
                               ax=fmaf(3.f,kx,ax); ay=fmaf(3.f,ky,ay); az=fmaf(3.f,kz,az); }
            else if (s == 2) { k3x=kx;k3y=ky;k3z=kz;
                               ax=fmaf(3.f,kx,ax); ay=fmaf(3.f,ky,ay); az=fmaf(3.f,kz,az); }
            else             { ax+=kx; ay+=ky; az+=kz; }
        }

        if (lane < 16) {
            y[gbase]            = fmaf(0.125f, ax, xc0);
            y[gbase + NPT]      = fmaf(0.125f, ay, xc1);
            y[gbase + 2 * NPT]  = fmaf(0.125f, az, xc2);
        }
    }
}

extern "C" void kernel_launch(void* const* d_in, const int* in_sizes, int n_in,
                              void* d_out, int out_size, void* d_ws, size_t ws_size,
                              hipStream_t stream) {
    (void)in_sizes; (void)n_in; (void)d_ws; (void)ws_size; (void)out_size;
    const float* x0    = (const float*)d_in[0];
    const float* h1_w  = (const float*)d_in[1];
    const float* h1_b  = (const float*)d_in[2];
    const float* g1_w  = (const float*)d_in[3];
    const float* g1_b  = (const float*)d_in[4];
    const float* h2_w  = (const float*)d_in[5];
    const float* h2_b  = (const float*)d_in[6];
    const float* g2_w  = (const float*)d_in[7];
    const float* g2_b  = (const float*)d_in[8];
    const float* out_w = (const float*)d_in[9];
    const float* out_b = (const float*)d_in[10];
    float* y = (float*)d_out;

    // one tile per block; 6250 blocks, 4 co-resident per CU
    node_rk4_mfma<<<NTILES, 256, 0, stream>>>(
        x0, h1_w, h1_b, g1_w, g1_b, h2_w, h2_b, g2_w, g2_b, out_w, out_b, y);
}

// Round 5
// 480.250 us; speedup vs baseline: 1.6752x; 1.6752x over previous
//
#include <hip/hip_runtime.h>
#include <math.h>
#include <utility>

typedef __attribute__((ext_vector_type(8))) short    bf16x8;
typedef __attribute__((ext_vector_type(4))) float    f32x4;
typedef __attribute__((ext_vector_type(2))) unsigned u32x2;
typedef __attribute__((ext_vector_type(4))) unsigned u32x4;

template<int I, int N, class F>
__device__ __forceinline__ void sfor(F&& f) {
    if constexpr (I < N) { f(std::integral_constant<int, I>{}); sfor<I + 1, N>(static_cast<F&&>(f)); }
}

#define NPT    50000
#define NTILES 6250     // 400000 pts / 64 per tile, exact
#define ZIN_S  40       // shorts per zin row (80 B = 5*16B)
#define Z_S    136      // shorts per z1/z2 row (272 B = 17*16B, odd 16B multiple)

static __device__ __forceinline__ float tanh_fast(float x) {
    float xc = fminf(fmaxf(x, -15.f), 15.f);
    float e  = __expf(2.f * xc);
    return __fdividef(e - 1.f, e + 1.f);
}
static __device__ __forceinline__ unsigned short bf16r(float f) {   // RNE f32->bf16
    unsigned u = __builtin_bit_cast(unsigned, f);
    u += 0x7FFFu + ((u >> 16) & 1u);
    return (unsigned short)(u >> 16);
}

#if defined(__has_builtin)
#if __has_builtin(__builtin_amdgcn_cvt_pk_bf16_f32)
#define HAVE_CVT_PK_BF16 1
#endif
#endif

static __device__ __forceinline__ unsigned packbf(float a, float b) {
#ifdef HAVE_CVT_PK_BF16
    return __builtin_bit_cast(unsigned, __builtin_amdgcn_cvt_pk_bf16_f32(a, b));
#else
    return (unsigned)bf16r(a) | ((unsigned)bf16r(b) << 16);
#endif
}
// gated activation: relu(h * sigmoid(g)) = max(h / (1 + e^-g), 0)   (denom > 0)
static __device__ __forceinline__ float gate(float h, float g) {
    return fmaxf(__fdividef(h, 1.f + __expf(-g)), 0.f);
}
static __device__ __forceinline__ bf16x8 pack8(const float* p) {   // p 16B-aligned
    f32x4 lo = *reinterpret_cast<const f32x4*>(p);
    f32x4 hi = *reinterpret_cast<const f32x4*>(p + 4);
    u32x4 u = { packbf(lo[0], lo[1]), packbf(lo[2], lo[3]),
                packbf(hi[0], hi[1]), packbf(hi[2], hi[3]) };
    return __builtin_bit_cast(bf16x8, u);
}
static __device__ __forceinline__ f32x4 mfma16(bf16x8 a, bf16x8 b, f32x4 c) {
    return __builtin_amdgcn_mfma_f32_16x16x32_bf16(a, b, c, 0, 0, 0);
}

// Block = 512 thr = 8 waves, one 64-point tile per block.
// Wave w owns channel rows [16w, 16w+16) for layers 1&2 (A-frags + biases
// resident: ~76 regs). Waves 0-3 additionally own points [16w,16w+16) for
// RK4 state / out-layer / global I/O. Activations pass through LDS in B-frag
// layout [p][k]. Peak live set ~125 regs -> fits 128 cap of (512,4):
// 2 blocks/CU = 16 waves/CU, LDS 2*39936 <= 160 KiB.
__global__ __launch_bounds__(512, 4) void node_rk4_mfma(
    const float* __restrict__ x0,
    const float* __restrict__ h1_w, const float* __restrict__ h1_b,
    const float* __restrict__ g1_w, const float* __restrict__ g1_b,
    const float* __restrict__ h2_w, const float* __restrict__ h2_b,
    const float* __restrict__ g2_w, const float* __restrict__ g2_b,
    const float* __restrict__ out_w, const float* __restrict__ out_b,
    float* __restrict__ y)
{
    __shared__ __align__(16) short zin[64 * ZIN_S];
    __shared__ __align__(16) short z1s[64 * Z_S];
    __shared__ __align__(16) short z2s[64 * Z_S];

    const int tid  = threadIdx.x;
    const int w    = tid >> 6;        // wave id 0..7
    const int lane = tid & 63;
    const int q    = lane >> 4;       // quad 0..3
    const int m    = lane & 15;       // MFMA row (A) / col (B,C)

    // ---------------- weight preload (once per block) ----------------
    const int row = 16 * w + m;                 // this lane's A-row (channel)
    bf16x8 a2h[4], a2g[4];                      // layer2 A-frags per k-step
    sfor<0, 4>([&](auto KS) {
        constexpr int ks = KS.value;
        a2h[ks] = pack8(h2_w + row * 128 + ks * 32 + q * 8);
        a2g[ks] = pack8(g2_w + row * 128 + ks * 32 + q * 8);
    });
    bf16x8 a1h = {0,0,0,0,0,0,0,0}, a1g = {0,0,0,0,0,0,0,0};
    if (q == 0) {
        f32x4 t1 = *reinterpret_cast<const f32x4*>(h1_w + row * 4);
        f32x4 t2 = *reinterpret_cast<const f32x4*>(g1_w + row * 4);
        u32x4 u1 = { packbf(t1[0], t1[1]), packbf(t1[2], t1[3]), 0u, 0u };
        u32x4 u2 = { packbf(t2[0], t2[1]), packbf(t2[2], t2[3]), 0u, 0u };
        a1h = __builtin_bit_cast(bf16x8, u1);
        a1g = __builtin_bit_cast(bf16x8, u2);
    }
    bf16x8 aow[4];
    sfor<0, 4>([&](auto KS) {
        constexpr int ks = KS.value;
        bf16x8 t = {0,0,0,0,0,0,0,0};
        if (m < 3) t = pack8(out_w + m * 128 + ks * 32 + q * 8);
        aow[ks] = t;
    });
    // biases in C-frag layout: lane holds channel rows 16w + 4q + r
    const int cb = 16 * w + 4 * q;
    const f32x4 b2h = *reinterpret_cast<const f32x4*>(h2_b + cb);
    const f32x4 b2g = *reinterpret_cast<const f32x4*>(g2_b + cb);
    const f32x4 b1h = *reinterpret_cast<const f32x4*>(h1_b + cb);
    const f32x4 b1g = *reinterpret_cast<const f32x4*>(g1_b + cb);
    f32x4 vob = {0.f, 0.f, 0.f, 0.f};
    if (q == 0) { vob[0] = out_b[0]; vob[1] = out_b[1]; vob[2] = out_b[2]; }

    // zero zin (pad rows k=4..31 must be 0 for the K-padded layer1 MFMA)
    for (int i = tid; i < 64 * ZIN_S / 2; i += 512) ((unsigned*)zin)[i] = 0u;
    __syncthreads();

    const float third = 1.0f / 3.0f;
    const int tile = blockIdx.x;

    // RK4 state: waves 0-3, lanes 0-15 (point = tile*64 + w*16 + lane)
    float xc0 = 0.f, xc1 = 0.f, xc2 = 0.f;
    int gbase = 0;
    if (w < 4 && lane < 16) {
        const int pg = tile * 64 + w * 16 + lane;
        const int bb = pg / NPT;
        const int nn = pg - bb * NPT;
        gbase = bb * 3 * NPT + nn;
        xc0 = x0[gbase]; xc1 = x0[gbase + NPT]; xc2 = x0[gbase + 2 * NPT];
    }
    float k1x=0,k1y=0,k1z=0, k2x=0,k2y=0,k2z=0, k3x=0,k3y=0,k3z=0;
    float ax=0, ay=0, az=0;

    #pragma unroll 1
    for (int s = 0; s < 4; ++s) {
        // ---- stage input -> zin (B-frag rows; owner lanes only) ----
        if (w < 4 && lane < 16) {
            float zi0, zi1, zi2, tt;
            if (s == 0)      { zi0 = xc0; zi1 = xc1; zi2 = xc2; tt = 0.f; }
            else if (s == 1) { zi0 = fmaf(k1x, third, xc0);
                               zi1 = fmaf(k1y, third, xc1);
                               zi2 = fmaf(k1z, third, xc2); tt = third; }
            else if (s == 2) { zi0 = xc0 + (k2x - k1x * third);
                               zi1 = xc1 + (k2y - k1y * third);
                               zi2 = xc2 + (k2z - k1z * third); tt = 2.f * third; }
            else             { zi0 = xc0 + (k1x - k2x + k3x);
                               zi1 = xc1 + (k1y - k2y + k3y);
                               zi2 = xc2 + (k1z - k2z + k3z); tt = 1.f; }
            u32x2 pk = { packbf(zi0, zi1), packbf(zi2, tt) };
            *reinterpret_cast<u32x2*>(&zin[(w * 16 + lane) * ZIN_S]) = pk;
        }
        __syncthreads();

        // ---- layer 1 (4->128, K-padded MFMA); bias rides in as C operand ----
        f32x4 c1h[4], c1g[4];
        sfor<0, 4>([&](auto NT) {
            constexpr int nt = NT.value;
            bf16x8 bf = *reinterpret_cast<const bf16x8*>(&zin[(nt * 16 + m) * ZIN_S + q * 8]);
            c1h[nt] = mfma16(a1h, bf, b1h);
            c1g[nt] = mfma16(a1g, bf, b1g);
        });
        sfor<0, 4>([&](auto NT) {
            constexpr int nt = NT.value;
            f32x4 h = c1h[nt], g = c1g[nt];
            u32x2 pk = { packbf(gate(h[0], g[0]), gate(h[1], g[1])),
                         packbf(gate(h[2], g[2]), gate(h[3], g[3])) };
            *reinterpret_cast<u32x2*>(&z1s[(nt * 16 + m) * Z_S + 16 * w + 4 * q]) = pk;
        });
        __syncthreads();

        // ---- layer 2 (128->128); ks=0 uses bias as C, ks=1..3 accumulate ----
        f32x4 c2h[4], c2g[4];
        sfor<0, 4>([&](auto NT) {
            constexpr int nt = NT.value;
            bf16x8 bf = *reinterpret_cast<const bf16x8*>(&z1s[(nt * 16 + m) * Z_S + q * 8]);
            c2h[nt] = mfma16(a2h[0], bf, b2h);
            c2g[nt] = mfma16(a2g[0], bf, b2g);
        });
        sfor<1, 4>([&](auto KS) {
            constexpr int ks = KS.value;
            sfor<0, 4>([&](auto NT) {
                constexpr int nt = NT.value;
                bf16x8 bf = *reinterpret_cast<const bf16x8*>(&z1s[(nt * 16 + m) * Z_S + ks * 32 + q * 8]);
                c2h[nt] = mfma16(a2h[ks], bf, c2h[nt]);
                c2g[nt] = mfma16(a2g[ks], bf, c2g[nt]);
            });
        });
        sfor<0, 4>([&](auto NT) {
            constexpr int nt = NT.value;
            f32x4 h = c2h[nt], g = c2g[nt];
            u32x2 pk = { packbf(gate(h[0], g[0]), gate(h[1], g[1])),
                         packbf(gate(h[2], g[2]), gate(h[3], g[3])) };
            *reinterpret_cast<u32x2*>(&z2s[(nt * 16 + m) * Z_S + 16 * w + 4 * q]) = pk;
        });
        __syncthreads();

        // ---- out layer (128->3, M padded to 16); waves 0-3, 16 pts each ----
        if (w < 4) {
            f32x4 vc;
            {
                bf16x8 bf = *reinterpret_cast<const bf16x8*>(&z2s[(w * 16 + m) * Z_S + q * 8]);
                vc = mfma16(aow[0], bf, vob);
            }
            sfor<1, 4>([&](auto KS) {
                constexpr int ks = KS.value;
                bf16x8 bf = *reinterpret_cast<const bf16x8*>(&z2s[(w * 16 + m) * Z_S + ks * 32 + q * 8]);
                vc = mfma16(aow[ks], bf, vc);
            });
            // channels live in quad-0 regs 0..2 (C row = 4q+r)
            const float kx = tanh_fast(vc[0]) * 0.5f;
            const float ky = tanh_fast(vc[1]) * 0.5f;
            const float kz = tanh_fast(vc[2]) * 0.5f;

            if (s == 0)      { k1x=kx;k1y=ky;k1z=kz; ax=kx;ay=ky;az=kz; }
            else if (s == 1) { k2x=kx;k2y=ky;k2z=kz;
                               ax=fmaf(3.f,kx,ax); ay=fmaf(3.f,ky,ay); az=fmaf(3.f,kz,az); }
            else if (s == 2) { k3x=kx;k3y=ky;k3z=kz;
                               ax=fmaf(3.f,kx,ax); ay=fmaf(3.f,ky,ay); az=fmaf(3.f,kz,az); }
            else             { ax+=kx; ay+=ky; az+=kz; }
        }
    }

    if (w < 4 && lane < 16) {
        y[gbase]           = fmaf(0.125f, ax, xc0);
        y[gbase + NPT]     = fmaf(0.125f, ay, xc1);
        y[gbase + 2 * NPT] = fmaf(0.125f, az, xc2);
    }
}

extern "C" void kernel_launch(void* const* d_in, const int* in_sizes, int n_in,
                              void* d_out, int out_size, void* d_ws, size_t ws_size,
                              hipStream_t stream) {
    (void)in_sizes; (void)n_in; (void)d_ws; (void)ws_size; (void)out_size;
    const float* x0    = (const float*)d_in[0];
    const float* h1_w  = (const float*)d_in[1];
    const float* h1_b  = (const float*)d_in[2];
    const float* g1_w  = (const float*)d_in[3];
    const float* g1_b  = (const float*)d_in[4];
    const float* h2_w  = (const float*)d_in[5];
    const float* h2_b  = (const float*)d_in[6];
    const float* g2_w  = (const float*)d_in[7];
    const float* g2_b  = (const float*)d_in[8];
    const float* out_w = (const float*)d_in[9];
    const float* out_b = (const float*)d_in[10];
    float* y = (float*)d_out;

    // one 64-pt tile per 512-thread block
    node_rk4_mfma<<<NTILES, 512, 0, stream>>>(
        x0, h1_w, h1_b, g1_w, g1_b, h2_w, h2_b, g2_w, g2_b, out_w, out_b, y);
}

// Round 6
// 376.983 us; speedup vs baseline: 2.1341x; 1.2739x over previous
//
#include <hip/hip_runtime.h>
#include <math.h>
#include <utility>

typedef __attribute__((ext_vector_type(8))) short    bf16x8;
typedef __attribute__((ext_vector_type(4))) float    f32x4;
typedef __attribute__((ext_vector_type(2))) unsigned u32x2;
typedef __attribute__((ext_vector_type(4))) unsigned u32x4;

template<int I, int N, class F>
__device__ __forceinline__ void sfor(F&& f) {
    if constexpr (I < N) { f(std::integral_constant<int, I>{}); sfor<I + 1, N>(static_cast<F&&>(f)); }
}

#define NPT    50000
#define NTILES 6250     // 400000 pts / 64 per tile, exact
#define ZIN_S  40       // shorts per zin row (80 B = 5*16B)
#define Z_S    136      // shorts per z1/z2 row (272 B = 17*16B)

static __device__ __forceinline__ float tanh_fast(float x) {
    float xc = fminf(fmaxf(x, -15.f), 15.f);
    float e  = __expf(2.f * xc);
    return __fdividef(e - 1.f, e + 1.f);
}
static __device__ __forceinline__ unsigned short bf16r(float f) {   // RNE f32->bf16
    unsigned u = __builtin_bit_cast(unsigned, f);
    u += 0x7FFFu + ((u >> 16) & 1u);
    return (unsigned short)(u >> 16);
}

#if defined(__has_builtin)
#if __has_builtin(__builtin_amdgcn_cvt_pk_bf16_f32)
#define HAVE_CVT_PK_BF16 1
#endif
#endif

static __device__ __forceinline__ unsigned packbf(float a, float b) {
#ifdef HAVE_CVT_PK_BF16
    return __builtin_bit_cast(unsigned, __builtin_amdgcn_cvt_pk_bf16_f32(a, b));
#else
    return (unsigned)bf16r(a) | ((unsigned)bf16r(b) << 16);
#endif
}
// gated activation: relu(h * sigmoid(g)) = max(h / (1 + e^-g), 0)   (denom > 0)
static __device__ __forceinline__ float gate(float h, float g) {
    return fmaxf(__fdividef(h, 1.f + __expf(-g)), 0.f);
}
static __device__ __forceinline__ bf16x8 pack8(const float* p) {   // p 16B-aligned
    f32x4 lo = *reinterpret_cast<const f32x4*>(p);
    f32x4 hi = *reinterpret_cast<const f32x4*>(p + 4);
    u32x4 u = { packbf(lo[0], lo[1]), packbf(lo[2], lo[3]),
                packbf(hi[0], hi[1]), packbf(hi[2], hi[3]) };
    return __builtin_bit_cast(bf16x8, u);
}
static __device__ __forceinline__ f32x4 mfma16(bf16x8 a, bf16x8 b, f32x4 c) {
    return __builtin_amdgcn_mfma_f32_16x16x32_bf16(a, b, c, 0, 0, 0);
}

// Block = 512 thr = 8 waves, one 64-point tile per block.
// Wave w owns channel rows [16w, 16w+16) (A-frags + biases resident ~56 regs).
// Waves 0-3 own points [16w,16w+16) for RK4 state / out-layer / global I/O.
// Register-budget fixes vs round 5 (which spilled 369 MB):
//  - accumulators processed in 2 sequential n-chunks (unroll 1) -> 16 live, not 32
//  - out-layer A-frags live in LDS (built once), not 16 persistent VGPRs
// Peak live ~113 regs -> fits 128 cap of (512,4): 2 blocks/CU = 16 waves/CU.
__global__ __launch_bounds__(512, 4) void node_rk4_mfma(
    const float* __restrict__ x0,
    const float* __restrict__ h1_w, const float* __restrict__ h1_b,
    const float* __restrict__ g1_w, const float* __restrict__ g1_b,
    const float* __restrict__ h2_w, const float* __restrict__ h2_b,
    const float* __restrict__ g2_w, const float* __restrict__ g2_b,
    const float* __restrict__ out_w, const float* __restrict__ out_b,
    float* __restrict__ y)
{
    __shared__ __align__(16) short zin[64 * ZIN_S];
    __shared__ __align__(16) short z1s[64 * Z_S];
    __shared__ __align__(16) short z2s[64 * Z_S];
    __shared__ __align__(16) short aow_s[4 * 64 * 8];   // out-layer A-frags [ks][lane]

    const int tid  = threadIdx.x;
    const int w    = tid >> 6;        // wave id 0..7
    const int lane = tid & 63;
    const int q    = lane >> 4;       // quad 0..3
    const int m    = lane & 15;       // MFMA row (A) / col (B,C)

    // ---------------- weight preload (once per block) ----------------
    const int row = 16 * w + m;                 // this lane's A-row (channel)
    bf16x8 a2h[4], a2g[4];                      // layer2 A-frags per k-step
    sfor<0, 4>([&](auto KS) {
        constexpr int ks = KS.value;
        a2h[ks] = pack8(h2_w + row * 128 + ks * 32 + q * 8);
        a2g[ks] = pack8(g2_w + row * 128 + ks * 32 + q * 8);
    });
    bf16x8 a1h = {0,0,0,0,0,0,0,0}, a1g = {0,0,0,0,0,0,0,0};
    if (q == 0) {
        f32x4 t1 = *reinterpret_cast<const f32x4*>(h1_w + row * 4);
        f32x4 t2 = *reinterpret_cast<const f32x4*>(g1_w + row * 4);
        u32x4 u1 = { packbf(t1[0], t1[1]), packbf(t1[2], t1[3]), 0u, 0u };
        u32x4 u2 = { packbf(t2[0], t2[1]), packbf(t2[2], t2[3]), 0u, 0u };
        a1h = __builtin_bit_cast(bf16x8, u1);
        a1g = __builtin_bit_cast(bf16x8, u2);
    }
    // out-layer A-frags -> LDS (wave 0 builds; lane-linear, conflict-free reads)
    if (w == 0) {
        sfor<0, 4>([&](auto KS) {
            constexpr int ks = KS.value;
            bf16x8 t = {0,0,0,0,0,0,0,0};
            if (m < 3) t = pack8(out_w + m * 128 + ks * 32 + q * 8);
            *reinterpret_cast<bf16x8*>(&aow_s[(ks * 64 + lane) * 8]) = t;
        });
    }
    // biases in C-frag layout: lane holds channel rows 16w + 4q + r
    const int cb = 16 * w + 4 * q;
    const f32x4 b2h = *reinterpret_cast<const f32x4*>(h2_b + cb);
    const f32x4 b2g = *reinterpret_cast<const f32x4*>(g2_b + cb);
    const f32x4 b1h = *reinterpret_cast<const f32x4*>(h1_b + cb);
    const f32x4 b1g = *reinterpret_cast<const f32x4*>(g1_b + cb);
    f32x4 vob = {0.f, 0.f, 0.f, 0.f};
    if (q == 0) { vob[0] = out_b[0]; vob[1] = out_b[1]; vob[2] = out_b[2]; }

    // zero zin (pad rows k=4..31 must be 0 for the K-padded layer1 MFMA)
    for (int i = tid; i < 64 * ZIN_S / 2; i += 512) ((unsigned*)zin)[i] = 0u;
    __syncthreads();

    const float third = 1.0f / 3.0f;
    const int tile = blockIdx.x;

    // RK4 state: waves 0-3, lanes 0-15 (point = tile*64 + w*16 + lane)
    float xc0 = 0.f, xc1 = 0.f, xc2 = 0.f;
    int gbase = 0;
    if (w < 4 && lane < 16) {
        const int pg = tile * 64 + w * 16 + lane;
        const int bb = pg / NPT;
        const int nn = pg - bb * NPT;
        gbase = bb * 3 * NPT + nn;
        xc0 = x0[gbase]; xc1 = x0[gbase + NPT]; xc2 = x0[gbase + 2 * NPT];
    }
    float k1x=0,k1y=0,k1z=0, k2x=0,k2y=0,k2z=0, k3x=0,k3y=0,k3z=0;
    float ax=0, ay=0, az=0;

    #pragma unroll 1
    for (int s = 0; s < 4; ++s) {
        // ---- stage input -> zin (B-frag rows; owner lanes only) ----
        if (w < 4 && lane < 16) {
            float zi0, zi1, zi2, tt;
            if (s == 0)      { zi0 = xc0; zi1 = xc1; zi2 = xc2; tt = 0.f; }
            else if (s == 1) { zi0 = fmaf(k1x, third, xc0);
                               zi1 = fmaf(k1y, third, xc1);
                               zi2 = fmaf(k1z, third, xc2); tt = third; }
            else if (s == 2) { zi0 = xc0 + (k2x - k1x * third);
                               zi1 = xc1 + (k2y - k1y * third);
                               zi2 = xc2 + (k2z - k1z * third); tt = 2.f * third; }
            else             { zi0 = xc0 + (k1x - k2x + k3x);
                               zi1 = xc1 + (k1y - k2y + k3y);
                               zi2 = xc2 + (k1z - k2z + k3z); tt = 1.f; }
            u32x2 pk = { packbf(zi0, zi1), packbf(zi2, tt) };
            *reinterpret_cast<u32x2*>(&zin[(w * 16 + lane) * ZIN_S]) = pk;
        }
        __syncthreads();

        // ---- layer 1 (4->128, K-padded MFMA), 2 n-chunks of 2 tiles ----
        #pragma unroll 1
        for (int ch = 0; ch < 2; ++ch) {
            f32x4 c1h[2], c1g[2];
            sfor<0, 2>([&](auto J) {
                constexpr int j = J.value;
                const int nt = 2 * ch + j;
                bf16x8 bf = *reinterpret_cast<const bf16x8*>(&zin[(nt * 16 + m) * ZIN_S + q * 8]);
                c1h[j] = mfma16(a1h, bf, b1h);
                c1g[j] = mfma16(a1g, bf, b1g);
            });
            sfor<0, 2>([&](auto J) {
                constexpr int j = J.value;
                const int nt = 2 * ch + j;
                f32x4 h = c1h[j], g = c1g[j];
                u32x2 pk = { packbf(gate(h[0], g[0]), gate(h[1], g[1])),
                             packbf(gate(h[2], g[2]), gate(h[3], g[3])) };
                *reinterpret_cast<u32x2*>(&z1s[(nt * 16 + m) * Z_S + 16 * w + 4 * q]) = pk;
            });
        }
        __syncthreads();

        // ---- layer 2 (128->128), 2 n-chunks; bias rides in as C on ks=0 ----
        #pragma unroll 1
        for (int ch = 0; ch < 2; ++ch) {
            f32x4 c2h[2], c2g[2];
            sfor<0, 2>([&](auto J) {
                constexpr int j = J.value;
                const int nt = 2 * ch + j;
                bf16x8 bf = *reinterpret_cast<const bf16x8*>(&z1s[(nt * 16 + m) * Z_S + q * 8]);
                c2h[j] = mfma16(a2h[0], bf, b2h);
                c2g[j] = mfma16(a2g[0], bf, b2g);
            });
            sfor<1, 4>([&](auto KS) {
                constexpr int ks = KS.value;
                sfor<0, 2>([&](auto J) {
                    constexpr int j = J.value;
                    const int nt = 2 * ch + j;
                    bf16x8 bf = *reinterpret_cast<const bf16x8*>(&z1s[(nt * 16 + m) * Z_S + ks * 32 + q * 8]);
                    c2h[j] = mfma16(a2h[ks], bf, c2h[j]);
                    c2g[j] = mfma16(a2g[ks], bf, c2g[j]);
                });
            });
            sfor<0, 2>([&](auto J) {
                constexpr int j = J.value;
                const int nt = 2 * ch + j;
                f32x4 h = c2h[j], g = c2g[j];
                u32x2 pk = { packbf(gate(h[0], g[0]), gate(h[1], g[1])),
                             packbf(gate(h[2], g[2]), gate(h[3], g[3])) };
                *reinterpret_cast<u32x2*>(&z2s[(nt * 16 + m) * Z_S + 16 * w + 4 * q]) = pk;
            });
        }
        __syncthreads();

        // ---- out layer (128->3, M padded to 16); waves 0-3, 16 pts each ----
        if (w < 4) {
            f32x4 vc = vob;
            sfor<0, 4>([&](auto KS) {
                constexpr int ks = KS.value;
                bf16x8 af = *reinterpret_cast<const bf16x8*>(&aow_s[(ks * 64 + lane) * 8]);
                bf16x8 bf = *reinterpret_cast<const bf16x8*>(&z2s[(w * 16 + m) * Z_S + ks * 32 + q * 8]);
                vc = mfma16(af, bf, vc);
            });
            // channels live in quad-0 regs 0..2 (C row = 4q+r)
            const float kx = tanh_fast(vc[0]) * 0.5f;
            const float ky = tanh_fast(vc[1]) * 0.5f;
            const float kz = tanh_fast(vc[2]) * 0.5f;

            if (s == 0)      { k1x=kx;k1y=ky;k1z=kz; ax=kx;ay=ky;az=kz; }
            else if (s == 1) { k2x=kx;k2y=ky;k2z=kz;
                               ax=fmaf(3.f,kx,ax); ay=fmaf(3.f,ky,ay); az=fmaf(3.f,kz,az); }
            else if (s == 2) { k3x=kx;k3y=ky;k3z=kz;
                               ax=fmaf(3.f,kx,ax); ay=fmaf(3.f,ky,ay); az=fmaf(3.f,kz,az); }
            else             { ax+=kx; ay+=ky; az+=kz; }
        }
    }

    if (w < 4 && lane < 16) {
        y[gbase]           = fmaf(0.125f, ax, xc0);
        y[gbase + NPT]     = fmaf(0.125f, ay, xc1);
        y[gbase + 2 * NPT] = fmaf(0.125f, az, xc2);
    }
}

extern "C" void kernel_launch(void* const* d_in, const int* in_sizes, int n_in,
                              void* d_out, int out_size, void* d_ws, size_t ws_size,
                              hipStream_t stream) {
    (void)in_sizes; (void)n_in; (void)d_ws; (void)ws_size; (void)out_size;
    const float* x0    = (const float*)d_in[0];
    const float* h1_w  = (const float*)d_in[1];
    const float* h1_b  = (const float*)d_in[2];
    const float* g1_w  = (const float*)d_in[3];
    const float* g1_b  = (const float*)d_in[4];
    const float* h2_w  = (const float*)d_in[5];
    const float* h2_b  = (const float*)d_in[6];
    const float* g2_w  = (const float*)d_in[7];
    const float* g2_b  = (const float*)d_in[8];
    const float* out_w = (const float*)d_in[9];
    const float* out_b = (const float*)d_in[10];
    float* y = (float*)d_out;

    // one 64-pt tile per 512-thread block
    node_rk4_mfma<<<NTILES, 512, 0, stream>>>(
        x0, h1_w, h1_b, g1_w, g1_b, h2_w, h2_b, g2_w, g2_b, out_w, out_b, y);
}

// Round 7
// 306.484 us; speedup vs baseline: 2.6250x; 1.2300x over previous
//
#include <hip/hip_runtime.h>
#include <math.h>
#include <utility>

typedef __attribute__((ext_vector_type(8))) short    bf16x8;
typedef __attribute__((ext_vector_type(4))) float    f32x4;
typedef __attribute__((ext_vector_type(2))) unsigned u32x2;
typedef __attribute__((ext_vector_type(4))) unsigned u32x4;

template<int I, int N, class F>
__device__ __forceinline__ void sfor(F&& f) {
    if constexpr (I < N) { f(std::integral_constant<int, I>{}); sfor<I + 1, N>(static_cast<F&&>(f)); }
}

#define NPT    50000
#define NTILES 6250     // 400000 pts / 64 per tile, exact
#define ZIN_S  40       // shorts per zin row (80 B = 5*16B)
#define Z_S    136      // shorts per z1/z2 row (272 B = 17*16B)

static __device__ __forceinline__ unsigned short bf16r(float f) {   // RNE f32->bf16
    unsigned u = __builtin_bit_cast(unsigned, f);
    u += 0x7FFFu + ((u >> 16) & 1u);
    return (unsigned short)(u >> 16);
}

#if defined(__has_builtin)
#if __has_builtin(__builtin_amdgcn_cvt_pk_bf16_f32)
#define HAVE_CVT_PK_BF16 1
#endif
#if __has_builtin(__builtin_amdgcn_exp2f) && __has_builtin(__builtin_amdgcn_rcpf)
#define HAVE_RAW_TRANS 1
#endif
#endif

static __device__ __forceinline__ unsigned packbf(float a, float b) {
#ifdef HAVE_CVT_PK_BF16
    return __builtin_bit_cast(unsigned, __builtin_amdgcn_cvt_pk_bf16_f32(a, b));
#else
    return (unsigned)bf16r(a) | ((unsigned)bf16r(b) << 16);
#endif
}

#define LOG2E 1.442695041f

#ifdef HAVE_RAW_TRANS
// raw v_exp_f32 / v_rcp_f32 — no OCML range-reduction, no IEEE-div sequence
static __device__ __forceinline__ float fexp2(float x) { return __builtin_amdgcn_exp2f(x); }
static __device__ __forceinline__ float frcp(float x)  { return __builtin_amdgcn_rcpf(x); }
#else
static __device__ __forceinline__ float fexp2(float x) { return __exp2f(x); }
static __device__ __forceinline__ float frcp(float x)  { return __frcp_rn(x); }
#endif

// gated activation: relu(h * sigmoid(g)) = max(h * rcp(1 + 2^(-g*log2e)), 0)
// 6 VALU instr (2 transcendental). denom in (1, inf) -> no NaN.
static __device__ __forceinline__ float gate(float h, float g) {
    return fmaxf(h * frcp(1.f + fexp2(g * -LOG2E)), 0.f);
}
// tanh(v)*0.5 = 0.5 - rcp(2^(2*log2e*v) + 1); exact limits at +-inf, no clamp.
static __device__ __forceinline__ float khalf(float v) {
    return 0.5f - frcp(fexp2(v * (2.f * LOG2E)) + 1.f);
}

static __device__ __forceinline__ bf16x8 pack8(const float* p) {   // p 16B-aligned
    f32x4 lo = *reinterpret_cast<const f32x4*>(p);
    f32x4 hi = *reinterpret_cast<const f32x4*>(p + 4);
    u32x4 u = { packbf(lo[0], lo[1]), packbf(lo[2], lo[3]),
                packbf(hi[0], hi[1]), packbf(hi[2], hi[3]) };
    return __builtin_bit_cast(bf16x8, u);
}
static __device__ __forceinline__ f32x4 mfma16(bf16x8 a, bf16x8 b, f32x4 c) {
    return __builtin_amdgcn_mfma_f32_16x16x32_bf16(a, b, c, 0, 0, 0);
}

// Block = 512 thr = 8 waves, one 64-point tile per block.
// Wave w owns channel rows [16w, 16w+16) (A-frags + biases resident ~56 regs).
// Waves 0-3 own points [16w,16w+16) for RK4 state / out-layer / global I/O.
// Round-6 structure (no spill, 2 blocks/CU); round-7 change: all transcendental
// math via raw v_exp_f32/v_rcp_f32 builtins (83% VALUBusy was libm expansion).
__global__ __launch_bounds__(512, 4) void node_rk4_mfma(
    const float* __restrict__ x0,
    const float* __restrict__ h1_w, const float* __restrict__ h1_b,
    const float* __restrict__ g1_w, const float* __restrict__ g1_b,
    const float* __restrict__ h2_w, const float* __restrict__ h2_b,
    const float* __restrict__ g2_w, const float* __restrict__ g2_b,
    const float* __restrict__ out_w, const float* __restrict__ out_b,
    float* __restrict__ y)
{
    __shared__ __align__(16) short zin[64 * ZIN_S];
    __shared__ __align__(16) short z1s[64 * Z_S];
    __shared__ __align__(16) short z2s[64 * Z_S];
    __shared__ __align__(16) short aow_s[4 * 64 * 8];   // out-layer A-frags [ks][lane]

    const int tid  = threadIdx.x;
    const int w    = tid >> 6;        // wave id 0..7
    const int lane = tid & 63;
    const int q    = lane >> 4;       // quad 0..3
    const int m    = lane & 15;       // MFMA row (A) / col (B,C)

    // ---------------- weight preload (once per block) ----------------
    const int row = 16 * w + m;                 // this lane's A-row (channel)
    bf16x8 a2h[4], a2g[4];                      // layer2 A-frags per k-step
    sfor<0, 4>([&](auto KS) {
        constexpr int ks = KS.value;
        a2h[ks] = pack8(h2_w + row * 128 + ks * 32 + q * 8);
        a2g[ks] = pack8(g2_w + row * 128 + ks * 32 + q * 8);
    });
    bf16x8 a1h = {0,0,0,0,0,0,0,0}, a1g = {0,0,0,0,0,0,0,0};
    if (q == 0) {
        f32x4 t1 = *reinterpret_cast<const f32x4*>(h1_w + row * 4);
        f32x4 t2 = *reinterpret_cast<const f32x4*>(g1_w + row * 4);
        u32x4 u1 = { packbf(t1[0], t1[1]), packbf(t1[2], t1[3]), 0u, 0u };
        u32x4 u2 = { packbf(t2[0], t2[1]), packbf(t2[2], t2[3]), 0u, 0u };
        a1h = __builtin_bit_cast(bf16x8, u1);
        a1g = __builtin_bit_cast(bf16x8, u2);
    }
    // out-layer A-frags -> LDS (wave 0 builds; lane-linear, conflict-free reads)
    if (w == 0) {
        sfor<0, 4>([&](auto KS) {
            constexpr int ks = KS.value;
            bf16x8 t = {0,0,0,0,0,0,0,0};
            if (m < 3) t = pack8(out_w + m * 128 + ks * 32 + q * 8);
            *reinterpret_cast<bf16x8*>(&aow_s[(ks * 64 + lane) * 8]) = t;
        });
    }
    // biases in C-frag layout: lane holds channel rows 16w + 4q + r
    const int cb = 16 * w + 4 * q;
    const f32x4 b2h = *reinterpret_cast<const f32x4*>(h2_b + cb);
    const f32x4 b2g = *reinterpret_cast<const f32x4*>(g2_b + cb);
    const f32x4 b1h = *reinterpret_cast<const f32x4*>(h1_b + cb);
    const f32x4 b1g = *reinterpret_cast<const f32x4*>(g1_b + cb);
    f32x4 vob = {0.f, 0.f, 0.f, 0.f};
    if (q == 0) { vob[0] = out_b[0]; vob[1] = out_b[1]; vob[2] = out_b[2]; }

    // zero zin (pad rows k=4..31 must be 0 for the K-padded layer1 MFMA)
    for (int i = tid; i < 64 * ZIN_S / 2; i += 512) ((unsigned*)zin)[i] = 0u;
    __syncthreads();

    const float third = 1.0f / 3.0f;
    const int tile = blockIdx.x;

    // RK4 state: waves 0-3, lanes 0-15 (point = tile*64 + w*16 + lane)
    float xc0 = 0.f, xc1 = 0.f, xc2 = 0.f;
    int gbase = 0;
    if (w < 4 && lane < 16) {
        const int pg = tile * 64 + w * 16 + lane;
        const int bb = pg / NPT;
        const int nn = pg - bb * NPT;
        gbase = bb * 3 * NPT + nn;
        xc0 = x0[gbase]; xc1 = x0[gbase + NPT]; xc2 = x0[gbase + 2 * NPT];
    }
    float k1x=0,k1y=0,k1z=0, k2x=0,k2y=0,k2z=0, k3x=0,k3y=0,k3z=0;
    float ax=0, ay=0, az=0;

    #pragma unroll 1
    for (int s = 0; s < 4; ++s) {
        // ---- stage input -> zin (B-frag rows; owner lanes only) ----
        if (w < 4 && lane < 16) {
            float zi0, zi1, zi2, tt;
            if (s == 0)      { zi0 = xc0; zi1 = xc1; zi2 = xc2; tt = 0.f; }
            else if (s == 1) { zi0 = fmaf(k1x, third, xc0);
                               zi1 = fmaf(k1y, third, xc1);
                               zi2 = fmaf(k1z, third, xc2); tt = third; }
            else if (s == 2) { zi0 = xc0 + (k2x - k1x * third);
                               zi1 = xc1 + (k2y - k1y * third);
                               zi2 = xc2 + (k2z - k1z * third); tt = 2.f * third; }
            else             { zi0 = xc0 + (k1x - k2x + k3x);
                               zi1 = xc1 + (k1y - k2y + k3y);
                               zi2 = xc2 + (k1z - k2z + k3z); tt = 1.f; }
            u32x2 pk = { packbf(zi0, zi1), packbf(zi2, tt) };
            *reinterpret_cast<u32x2*>(&zin[(w * 16 + lane) * ZIN_S]) = pk;
        }
        __syncthreads();

        // ---- layer 1 (4->128, K-padded MFMA), 2 n-chunks of 2 tiles ----
        #pragma unroll 1
        for (int ch = 0; ch < 2; ++ch) {
            f32x4 c1h[2], c1g[2];
            sfor<0, 2>([&](auto J) {
                constexpr int j = J.value;
                const int nt = 2 * ch + j;
                bf16x8 bf = *reinterpret_cast<const bf16x8*>(&zin[(nt * 16 + m) * ZIN_S + q * 8]);
                c1h[j] = mfma16(a1h, bf, b1h);
                c1g[j] = mfma16(a1g, bf, b1g);
            });
            sfor<0, 2>([&](auto J) {
                constexpr int j = J.value;
                const int nt = 2 * ch + j;
                f32x4 h = c1h[j], g = c1g[j];
                u32x2 pk = { packbf(gate(h[0], g[0]), gate(h[1], g[1])),
                             packbf(gate(h[2], g[2]), gate(h[3], g[3])) };
                *reinterpret_cast<u32x2*>(&z1s[(nt * 16 + m) * Z_S + 16 * w + 4 * q]) = pk;
            });
        }
        __syncthreads();

        // ---- layer 2 (128->128), 2 n-chunks; bias rides in as C on ks=0 ----
        #pragma unroll 1
        for (int ch = 0; ch < 2; ++ch) {
            f32x4 c2h[2], c2g[2];
            sfor<0, 2>([&](auto J) {
                constexpr int j = J.value;
                const int nt = 2 * ch + j;
                bf16x8 bf = *reinterpret_cast<const bf16x8*>(&z1s[(nt * 16 + m) * Z_S + q * 8]);
                c2h[j] = mfma16(a2h[0], bf, b2h);
                c2g[j] = mfma16(a2g[0], bf, b2g);
            });
            sfor<1, 4>([&](auto KS) {
                constexpr int ks = KS.value;
                sfor<0, 2>([&](auto J) {
                    constexpr int j = J.value;
                    const int nt = 2 * ch + j;
                    bf16x8 bf = *reinterpret_cast<const bf16x8*>(&z1s[(nt * 16 + m) * Z_S + ks * 32 + q * 8]);
                    c2h[j] = mfma16(a2h[ks], bf, c2h[j]);
                    c2g[j] = mfma16(a2g[ks], bf, c2g[j]);
                });
            });
            sfor<0, 2>([&](auto J) {
                constexpr int j = J.value;
                const int nt = 2 * ch + j;
                f32x4 h = c2h[j], g = c2g[j];
                u32x2 pk = { packbf(gate(h[0], g[0]), gate(h[1], g[1])),
                             packbf(gate(h[2], g[2]), gate(h[3], g[3])) };
                *reinterpret_cast<u32x2*>(&z2s[(nt * 16 + m) * Z_S + 16 * w + 4 * q]) = pk;
            });
        }
        __syncthreads();

        // ---- out layer (128->3, M padded to 16); waves 0-3, 16 pts each ----
        if (w < 4) {
            f32x4 vc = vob;
            sfor<0, 4>([&](auto KS) {
                constexpr int ks = KS.value;
                bf16x8 af = *reinterpret_cast<const bf16x8*>(&aow_s[(ks * 64 + lane) * 8]);
                bf16x8 bf = *reinterpret_cast<const bf16x8*>(&z2s[(w * 16 + m) * Z_S + ks * 32 + q * 8]);
                vc = mfma16(af, bf, vc);
            });
            // channels live in quad-0 regs 0..2 (C row = 4q+r); khalf = tanh*0.5
            const float kx = khalf(vc[0]);
            const float ky = khalf(vc[1]);
            const float kz = khalf(vc[2]);

            if (s == 0)      { k1x=kx;k1y=ky;k1z=kz; ax=kx;ay=ky;az=kz; }
            else if (s == 1) { k2x=kx;k2y=ky;k2z=kz;
                               ax=fmaf(3.f,kx,ax); ay=fmaf(3.f,ky,ay); az=fmaf(3.f,kz,az); }
            else if (s == 2) { k3x=kx;k3y=ky;k3z=kz;
                               ax=fmaf(3.f,kx,ax); ay=fmaf(3.f,ky,ay); az=fmaf(3.f,kz,az); }
            else             { ax+=kx; ay+=ky; az+=kz; }
        }
    }

    if (w < 4 && lane < 16) {
        y[gbase]           = fmaf(0.125f, ax, xc0);
        y[gbase + NPT]     = fmaf(0.125f, ay, xc1);
        y[gbase + 2 * NPT] = fmaf(0.125f, az, xc2);
    }
}

extern "C" void kernel_launch(void* const* d_in, const int* in_sizes, int n_in,
                              void* d_out, int out_size, void* d_ws, size_t ws_size,
                              hipStream_t stream) {
    (void)in_sizes; (void)n_in; (void)d_ws; (void)ws_size; (void)out_size;
    const float* x0    = (const float*)d_in[0];
    const float* h1_w  = (const float*)d_in[1];
    const float* h1_b  = (const float*)d_in[2];
    const float* g1_w  = (const float*)d_in[3];
    const float* g1_b  = (const float*)d_in[4];
    const float* h2_w  = (const float*)d_in[5];
    const float* h2_b  = (const float*)d_in[6];
    const float* g2_w  = (const float*)d_in[7];
    const float* g2_b  = (const float*)d_in[8];
    const float* out_w = (const float*)d_in[9];
    const float* out_b = (const float*)d_in[10];
    float* y = (float*)d_out;

    // one 64-pt tile per 512-thread block
    node_rk4_mfma<<<NTILES, 512, 0, stream>>>(
        x0, h1_w, h1_b, g1_w, g1_b, h2_w, h2_b, g2_w, g2_b, out_w, out_b, y);
}